// Round 14
// baseline (150.751 us; speedup 1.0000x reference)
//
#include <hip/hip_runtime.h>
#include <hip/hip_bf16.h>
#include <hip/hip_fp16.h>
#include <stdint.h>

#define K_DIM 4096
#define N_DIM 11008
#define M_DIM 512
#define PK_ROW 5504          // int32 code-words per k-row (one per n-pair)
#define SC_ROW 172           // scale blocks per k-row

typedef __attribute__((ext_vector_type(4))) float f32x4;
typedef __attribute__((ext_vector_type(4))) int i32x4;
typedef __attribute__((ext_vector_type(4))) unsigned int u32x4;
typedef __attribute__((ext_vector_type(8))) _Float16 half8;
typedef __attribute__((ext_vector_type(8))) short bf16x8;

__constant__ float NF4[16] = {
    -1.0f, -0.6961928009986877f, -0.5250730514526367f, -0.39491748809814453f,
    -0.28444138169288635f, -0.18477343022823334f, -0.09105003625154495f, 0.0f,
    0.07958029955625534f, 0.16093020141124725f, 0.24611230194568634f,
    0.33791524171829224f, 0.44070982933044434f, 0.5626170039176941f,
    0.7229568362236023f, 1.0f};

union H8 { u32x4 v; half8 h; };

__device__ __forceinline__ unsigned h2mul(unsigned a, unsigned b) {
  union { __half2 h; unsigned u; } x, y, r;
  x.u = a; y.u = b;
  r.h = x.h * y.h;           // v_pk_mul_f16
  return r.u;
}
__device__ __forceinline__ unsigned hpack(float a, float b) {
  union { __half2 h; unsigned u; } c;
  c.h = __floats2half2_rn(a, b);
  return c.u;
}
__device__ __forceinline__ unsigned f2bf(float v) {  // for fallback kernel
  union { __hip_bfloat16 h; unsigned short u; } cv;
  cv.h = __float2bfloat16(v);
  return (unsigned)cv.u;
}

// ---- merged pre-pass: codes transpose + A conv + scales pack ----
__global__ __launch_bounds__(256) void prep_all(
    const float* __restrict__ x, const int* __restrict__ packed,
    const float* __restrict__ scales, unsigned* __restrict__ wsa,
    unsigned* __restrict__ codes, unsigned* __restrict__ scalesp) {
  const int bid = blockIdx.x;
  const int t = threadIdx.x;
  if (bid < 5504) {
    // codes: out dword D = ((n>>4)*512 + (kp>>2))*16 + (n&15);
    // byte (n,kp) = code(2kp,n)<<4 | code(2kp+1,n)
    const int kt = bid & 63;
    const int nt = bid >> 6;
    __shared__ unsigned char Sb[128 * 36];
    const int npl = t & 63;
    const int kq = t >> 6;
    const int np = nt * 64 + npl;
#pragma unroll
    for (int i = 0; i < 8; ++i) {
      const int kpl = kq + i * 4;
      const int k = kt * 64 + kpl * 2;
      const int w0 = packed[(size_t)k * PK_ROW + np];
      const int w1 = packed[(size_t)(k + 1) * PK_ROW + np];
      Sb[(npl * 2) * 36 + kpl] =
          (unsigned char)((((w0 >> 4) & 15) << 4) | ((w1 >> 4) & 15));
      Sb[(npl * 2 + 1) * 36 + kpl] =
          (unsigned char)(((w0 & 15) << 4) | (w1 & 15));
    }
    __syncthreads();
#pragma unroll
    for (int i = 0; i < 4; ++i) {
      const int lin = t + 256 * i;
      const int n16 = lin & 15;
      const int kp4l = (lin >> 4) & 7;
      const int nb16l = lin >> 7;
      const unsigned v = *(const unsigned*)(Sb + (nb16l * 16 + n16) * 36 + kp4l * 4);
      const size_t D = ((size_t)(nt * 8 + nb16l) * 512 + kt * 8 + kp4l) * 16 + n16;
      codes[D] = v;
    }
  } else if (bid < 6528) {
    // conv_a: unit (m16,k32)=1KB; lane l holds A[m16*16+(l&15)][k32*32+(l>>4)*8..+8)
    const int wid = (bid - 5504) * 4 + (t >> 6);
    const int lane = t & 63;
    const int m16 = wid >> 7, k32 = wid & 127;
    const int m = m16 * 16 + (lane & 15);
    const int k = k32 * 32 + (lane >> 4) * 8;
    const float* src = x + (size_t)m * K_DIM + k;
    f32x4 v0 = *(const f32x4*)src;
    f32x4 v1 = *(const f32x4*)(src + 4);
    u32x4 d;
    d[0] = hpack(v0[0], v0[1]);
    d[1] = hpack(v0[2], v0[3]);
    d[2] = hpack(v1[0], v1[1]);
    d[3] = hpack(v1[2], v1[3]);
    *(u32x4*)(wsa + (size_t)wid * 256 + lane * 4) = d;
  } else {
    const int g = (bid - 6528) * 256 + t;
    if (g < SC_ROW * 2048) {
      const int kp = g / SC_ROW;
      const int nb = g - kp * SC_ROW;
      const float s0 = scales[(size_t)(2 * kp) * SC_ROW + nb];
      const float s1 = scales[(size_t)(2 * kp + 1) * SC_ROW + nb];
      scalesp[(size_t)nb * 2048 + kp] = hpack(s0, s1);
    }
  }
}

// ---- main: fused NF4 GEMM, f16 MFMA, software-pipelined DEQ/MMA ----
// R14: R9/R11/R12 pinned at 67us with busy-times SUMMING (VALU 24.5 + LDS 26
// + MFMA 19 ~= 69) -> per-wave gather->mul->MFMA chain serialized all pipes;
// TLP never broke it (3 configs). Fix = ILP: DEQ(s+1)'s 16 gathers issue
// BEFORE MMA(s)'s 16 MFMAs (~78cyc cover ~120cyc gather latency); codes 4-deep
// named prefetch, A 2-deep. VGPR ~190 (2 waves/SIMD) is the price; LDS-pipe
// floor 26.7us is the target.
template <int KS>
__global__ __launch_bounds__(256) void nf4_gemm16(
    const unsigned* __restrict__ codes, const unsigned* __restrict__ scalesp,
    const unsigned* __restrict__ wsa, const float* __restrict__ bias,
    float* __restrict__ cout) {
  __shared__ unsigned LutR[256 * 32];  // 32-copy replicated LUT (0 conflicts)

  const int bid = blockIdx.x;
  const int x = bid & 7;
  const int local = bid >> 3;
  const int kh = (KS > 1) ? (local & (KS - 1)) : 0;
  const int q = local / KS;            // 0..42
  const int tile = x * 43 + q;         // XCD x owns one m-slice
  const int m_tile = (tile / 86) * 128;
  const int n_tile = (tile % 86) * 128;

  const int t = threadIdx.x;
  {
    const int c = t & 31;
    const int b0 = t >> 5;
#pragma unroll
    for (int i = 0; i < 32; ++i) {
      const int b = b0 + 8 * i;
      LutR[b * 32 + c] = hpack(NF4[(b >> 4) & 15], NF4[b & 15]);
    }
  }
  __syncthreads();  // LUT visible; only barrier in the kernel

  const int lane = t & 63;
  const int wid = t >> 6;
  const int wm2 = wid >> 1;
  const int wnh = wid & 1;
  const int l15 = lane & 15;
  const int kslice = lane >> 4;
  const int lb = lane & 31;
  const int m16w = (m_tile >> 4) + wm2 * 4;
  const int nf0 = (n_tile >> 4) + wnh * 4;
  const int nb64 = (n_tile >> 6) + wnh;

  unsigned cb[4];
#pragma unroll
  for (int j = 0; j < 4; ++j) cb[j] = (unsigned)(nf0 + j) * 8192 + lane;
  const unsigned sb = (unsigned)nb64 * 2048 + kslice * 4;
  unsigned ab[4];
#pragma unroll
  for (int fm = 0; fm < 4; ++fm)
    ab[fm] = (unsigned)(m16w + fm) * 32768 + lane * 4;

  f32x4 acc[4][4];
#pragma unroll
  for (int i = 0; i < 4; ++i)
#pragma unroll
    for (int j = 0; j < 4; ++j) acc[i][j] = (f32x4){0.f, 0.f, 0.f, 0.f};

  const int NS = 128 / KS;             // k32-steps per block (mult of 4)
  const int s_base = kh * NS;

  auto LOADCS = [&](int sl, unsigned* c, u32x4& sv) {
    const unsigned s = (unsigned)(s_base + sl);
#pragma unroll
    for (int j = 0; j < 4; ++j) c[j] = codes[cb[j] + 64u * s];
    sv = *(const u32x4*)(scalesp + sb + 16u * s);
  };
  auto LOADA = [&](int sl, u32x4* A) {
    const unsigned s = (unsigned)(s_base + sl);
#pragma unroll
    for (int i = 0; i < 4; ++i) A[i] = *(const u32x4*)(wsa + ab[i] + 256u * s);
  };
  auto DEQ = [&](const unsigned* c, const u32x4& sv, u32x4* B) {
#pragma unroll
    for (int j = 0; j < 4; ++j) {
      const unsigned cw = c[j];
      B[j][0] = h2mul(LutR[((cw & 255u) << 5) | lb], sv[0]);
      B[j][1] = h2mul(LutR[(((cw >> 8) & 255u) << 5) | lb], sv[1]);
      B[j][2] = h2mul(LutR[(((cw >> 16) & 255u) << 5) | lb], sv[2]);
      B[j][3] = h2mul(LutR[((cw >> 24) << 5) | lb], sv[3]);
    }
  };
  auto MMA = [&](const u32x4* A, const u32x4* B) {
    H8 a[4], b[4];
#pragma unroll
    for (int i = 0; i < 4; ++i) a[i].v = A[i];
#pragma unroll
    for (int j = 0; j < 4; ++j) b[j].v = B[j];
#pragma unroll
    for (int j = 0; j < 4; ++j)
#pragma unroll
      for (int i = 0; i < 4; ++i)
        acc[i][j] = __builtin_amdgcn_mfma_f32_16x16x32_f16(a[i].h, b[j].h, acc[i][j], 0, 0, 0);
  };

  // pipeline state: codes/scales 4-deep (C0..C3), A 2-deep (AX,AY),
  // dequanted B 2-deep (BX,BY). All static-indexed (no scratch).
  unsigned C0[4], C1[4], C2[4], C3[4];
  u32x4 S0, S1, S2, S3;
  u32x4 AX[4], AY[4], BX[4], BY[4];

  LOADCS(0, C0, S0);
  LOADCS(1, C1, S1);
  LOADCS(2, C2, S2);
  LOADCS(3, C3, S3);
  LOADA(0, AX);
  LOADA(1, AY);
  DEQ(C0, S0, BX);                     // step 0

#pragma unroll 1
  for (int s = 0; s < NS; s += 4) {
    const bool tail = (s + 4 >= NS);
    DEQ(C1, S1, BY);                   // deq s+1 (gathers fly under MMA s)
    MMA(AX, BX);                       // s
    if (!tail) LOADCS(s + 4, C0, S0);
    LOADA(s + 2, AX);                  // s+2 <= NS-2 always
    DEQ(C2, S2, BX);                   // deq s+2
    MMA(AY, BY);                       // s+1
    if (!tail) LOADCS(s + 5, C1, S1);
    LOADA(s + 3, AY);                  // s+3 <= NS-1 always
    DEQ(C3, S3, BY);                   // deq s+3
    MMA(AX, BX);                       // s+2
    if (!tail) {
      LOADCS(s + 6, C2, S2);
      LOADA(s + 4, AX);
      DEQ(C0, S0, BX);                 // deq s+4 (C0 loaded ~8 slots ago)
    }
    MMA(AY, BY);                       // s+3
    if (!tail) {
      LOADCS(s + 7, C3, S3);
      LOADA(s + 5, AY);
    }
  }

  // epilogue: partial (or final for KS=1); C layout col=l15, row=kslice*4+r
  float* dst = cout + (size_t)kh * ((size_t)M_DIM * N_DIM);
#pragma unroll
  for (int j = 0; j < 4; ++j) {
    const int gc = n_tile + wnh * 64 + j * 16 + l15;
    const float bi = (KS == 1) ? bias[gc] : 0.f;
#pragma unroll
    for (int fm = 0; fm < 4; ++fm) {
#pragma unroll
      for (int r = 0; r < 4; ++r) {
        const int gr = m_tile + wm2 * 64 + fm * 16 + kslice * 4 + r;
        dst[(size_t)gr * N_DIM + gc] = acc[fm][j][r] + bi;
      }
    }
  }
}

// ---- reduce: out = p0+..+p(KS-1) + bias ----
template <int KS>
__global__ __launch_bounds__(256) void reduce_bias(
    const float* __restrict__ parts, const float* __restrict__ bias,
    float* __restrict__ out) {
  const int tot4 = (M_DIM * N_DIM) / 4;
  const int stride = gridDim.x * 256;
  const size_t MN = (size_t)M_DIM * N_DIM;
  for (int i = blockIdx.x * 256 + threadIdx.x; i < tot4; i += stride) {
    const int e0 = i * 4;
    const int col = e0 % N_DIM;
    f32x4 s = *(const f32x4*)(parts + e0);
#pragma unroll
    for (int p = 1; p < KS; ++p) s += *(const f32x4*)(parts + p * MN + e0);
    s += *(const f32x4*)(bias + col);
    *(f32x4*)(out + e0) = s;
  }
}

// ---- fallback (round-1 kernel, proven 155us): used only if ws tiny ----
#define FLDS 72
__global__ __launch_bounds__(256) void nf4_gemm_fused(
    const float* __restrict__ x, const int* __restrict__ packed,
    const float* __restrict__ scales, const float* __restrict__ bias,
    float* __restrict__ out) {
  __shared__ unsigned short AldsF[128 * FLDS];
  __shared__ unsigned short BldsF[128 * FLDS];
  __shared__ float2 Lut[256];
  const int t = threadIdx.x;
  const int bid = blockIdx.x;
  const int swz = (bid & 7) * 43 + (bid >> 3);
  const int m_tile = (swz / 86) * 128;
  const int n_tile = (swz % 86) * 128;
  Lut[t] = make_float2(NF4[(t >> 4) & 15], NF4[t & 15]);
  const int lane = t & 63;
  const int wid = t >> 6;
  const int wm = (wid >> 1) * 64;
  const int wn = (wid & 1) * 64;
  const int l15 = lane & 15;
  const int l4 = lane >> 4;
  f32x4 acc[4][4];
#pragma unroll
  for (int i = 0; i < 4; ++i)
#pragma unroll
    for (int j = 0; j < 4; ++j) acc[i][j] = (f32x4){0.f, 0.f, 0.f, 0.f};
  const int mlane = t & 15;
  const int n_sub = mlane * 8;
  const int k_sub = 4 * (((t >> 4) + mlane) & 15);
  const int c4 = t & 15;
  const int r0 = t >> 4;
  for (int k0 = 0; k0 < K_DIM; k0 += 64) {
    __syncthreads();
#pragma unroll
    for (int i = 0; i < 8; ++i) {
      const int row = r0 + 16 * i;
      f32x4 xv = *(const f32x4*)(x + (size_t)(m_tile + row) * K_DIM + k0 + c4 * 4);
      uint2 d;
      d.x = f2bf(xv[0]) | (f2bf(xv[1]) << 16);
      d.y = f2bf(xv[2]) | (f2bf(xv[3]) << 16);
      *(uint2*)(&AldsF[row * FLDS + c4 * 4]) = d;
    }
    {
      const int* pk = packed + (size_t)(k0 + k_sub) * PK_ROW + ((n_tile + n_sub) >> 1);
      i32x4 w[4];
      float s[4];
#pragma unroll
      for (int kk = 0; kk < 4; ++kk) {
        w[kk] = *(const i32x4*)(pk + (size_t)kk * PK_ROW);
        s[kk] = scales[(size_t)(k0 + k_sub + kk) * SC_ROW + ((n_tile + n_sub) >> 6)];
      }
      float v[4][8];
#pragma unroll
      for (int kk = 0; kk < 4; ++kk)
#pragma unroll
        for (int e = 0; e < 4; ++e) {
          const int b = w[kk][e] & 0xFF;
          const float2 p = Lut[b];
          v[kk][2 * e] = p.x * s[kk];
          v[kk][2 * e + 1] = p.y * s[kk];
        }
#pragma unroll
      for (int j = 0; j < 8; ++j) {
        uint2 d;
        d.x = f2bf(v[0][j]) | (f2bf(v[1][j]) << 16);
        d.y = f2bf(v[2][j]) | (f2bf(v[3][j]) << 16);
        *(uint2*)(&BldsF[(n_sub + j) * FLDS + k_sub]) = d;
      }
    }
    __syncthreads();
#pragma unroll
    for (int ks = 0; ks < 2; ++ks) {
      bf16x8 af[4], bfv[4];
#pragma unroll
      for (int fm = 0; fm < 4; ++fm)
        af[fm] = *(const bf16x8*)(&AldsF[(wm + fm * 16 + l15) * FLDS + ks * 32 + l4 * 8]);
#pragma unroll
      for (int fn = 0; fn < 4; ++fn)
        bfv[fn] = *(const bf16x8*)(&BldsF[(wn + fn * 16 + l15) * FLDS + ks * 32 + l4 * 8]);
#pragma unroll
      for (int fm = 0; fm < 4; ++fm)
#pragma unroll
        for (int fn = 0; fn < 4; ++fn)
          acc[fm][fn] = __builtin_amdgcn_mfma_f32_16x16x32_bf16(af[fm], bfv[fn], acc[fm][fn], 0, 0, 0);
    }
  }
#pragma unroll
  for (int fn = 0; fn < 4; ++fn) {
    const float bi = bias[n_tile + wn + fn * 16 + l15];
#pragma unroll
    for (int fm = 0; fm < 4; ++fm)
#pragma unroll
      for (int r = 0; r < 4; ++r) {
        const int gr = m_tile + wm + fm * 16 + l4 * 4 + r;
        out[(size_t)gr * N_DIM + n_tile + wn + fn * 16 + l15] = acc[fm][fn][r] + bi;
      }
  }
}

extern "C" void kernel_launch(void* const* d_in, const int* in_sizes, int n_in,
                              void* d_out, int out_size, void* d_ws, size_t ws_size,
                              hipStream_t stream) {
  const float* x = (const float*)d_in[0];
  const int* packed = (const int*)d_in[1];
  const float* scales = (const float*)d_in[2];
  const float* bias = (const float*)d_in[3];
  float* out = (float*)d_out;

  const size_t A_BYTES = (size_t)M_DIM * K_DIM * 2;            // 4,194,304
  const size_t C_BYTES = (size_t)688 * 512 * 16 * 4;           // 22,544,384
  const size_t S_BYTES = (size_t)SC_ROW * 2048 * 4;            // 1,409,024
  const size_t MN_BYTES = (size_t)M_DIM * N_DIM * 4;           // 22,544,384
  const size_t need1 = A_BYTES + C_BYTES + S_BYTES;            // 28.1 MB
  const size_t need2 = need1 + 2 * MN_BYTES;                   // 73.2 MB
  const size_t need4 = need1 + 4 * MN_BYTES;                   // 118.3 MB

  if (ws_size >= need1) {
    unsigned* wsa = (unsigned*)d_ws;
    unsigned* codes = (unsigned*)((char*)d_ws + A_BYTES);
    unsigned* scalesp = (unsigned*)((char*)d_ws + A_BYTES + C_BYTES);
    float* cpart = (float*)((char*)d_ws + need1);
    prep_all<<<dim3(7904), dim3(256), 0, stream>>>(x, packed, scales, wsa, codes, scalesp);
    if (ws_size >= need4) {
      nf4_gemm16<4><<<dim3(1376), dim3(256), 0, stream>>>(codes, scalesp, wsa, bias, cpart);
      reduce_bias<4><<<dim3(2048), dim3(256), 0, stream>>>(cpart, bias, out);
    } else if (ws_size >= need2) {
      nf4_gemm16<2><<<dim3(688), dim3(256), 0, stream>>>(codes, scalesp, wsa, bias, cpart);
      reduce_bias<2><<<dim3(2048), dim3(256), 0, stream>>>(cpart, bias, out);
    } else {
      nf4_gemm16<1><<<dim3(344), dim3(256), 0, stream>>>(codes, scalesp, wsa, bias, out);
    }
  } else {
    nf4_gemm_fused<<<dim3(344), dim3(256), 0, stream>>>(x, packed, scales, bias, out);
  }
}

// Round 15
// 127.032 us; speedup vs baseline: 1.1867x; 1.1867x over previous
//
#include <hip/hip_runtime.h>
#include <hip/hip_bf16.h>
#include <hip/hip_fp16.h>
#include <stdint.h>

#define K_DIM 4096
#define N_DIM 11008
#define M_DIM 512
#define PK_ROW 5504          // int32 code-words per k-row (one per n-pair)
#define SC_ROW 172           // scale blocks per k-row

typedef __attribute__((ext_vector_type(4))) float f32x4;
typedef __attribute__((ext_vector_type(4))) int i32x4;
typedef __attribute__((ext_vector_type(4))) unsigned int u32x4;
typedef __attribute__((ext_vector_type(8))) _Float16 half8;
typedef __attribute__((ext_vector_type(8))) short bf16x8;

__constant__ float NF4[16] = {
    -1.0f, -0.6961928009986877f, -0.5250730514526367f, -0.39491748809814453f,
    -0.28444138169288635f, -0.18477343022823334f, -0.09105003625154495f, 0.0f,
    0.07958029955625534f, 0.16093020141124725f, 0.24611230194568634f,
    0.33791524171829224f, 0.44070982933044434f, 0.5626170039176941f,
    0.7229568362236023f, 1.0f};

union H8 { u32x4 v; half8 h; };

__device__ __forceinline__ unsigned h2mul(unsigned a, unsigned b) {
  union { __half2 h; unsigned u; } x, y, r;
  x.u = a; y.u = b;
  r.h = x.h * y.h;           // v_pk_mul_f16
  return r.u;
}
__device__ __forceinline__ unsigned hpack(float a, float b) {
  union { __half2 h; unsigned u; } c;
  c.h = __floats2half2_rn(a, b);
  return c.u;
}
__device__ __forceinline__ unsigned f2bf(float v) {  // for fallback kernel
  union { __hip_bfloat16 h; unsigned short u; } cv;
  cv.h = __float2bfloat16(v);
  return (unsigned)cv.u;
}

// ---- merged pre-pass: codes transpose + A conv + scales pack ----
__global__ __launch_bounds__(256) void prep_all(
    const float* __restrict__ x, const int* __restrict__ packed,
    const float* __restrict__ scales, unsigned* __restrict__ wsa,
    unsigned* __restrict__ codes, unsigned* __restrict__ scalesp) {
  const int bid = blockIdx.x;
  const int t = threadIdx.x;
  if (bid < 5504) {
    // codes: out dword D = ((n>>4)*512 + (kp>>2))*16 + (n&15);
    // byte (n,kp) = code(2kp,n)<<4 | code(2kp+1,n)
    const int kt = bid & 63;
    const int nt = bid >> 6;
    __shared__ unsigned char Sb[128 * 36];
    const int npl = t & 63;
    const int kq = t >> 6;
    const int np = nt * 64 + npl;
#pragma unroll
    for (int i = 0; i < 8; ++i) {
      const int kpl = kq + i * 4;
      const int k = kt * 64 + kpl * 2;
      const int w0 = packed[(size_t)k * PK_ROW + np];
      const int w1 = packed[(size_t)(k + 1) * PK_ROW + np];
      Sb[(npl * 2) * 36 + kpl] =
          (unsigned char)((((w0 >> 4) & 15) << 4) | ((w1 >> 4) & 15));
      Sb[(npl * 2 + 1) * 36 + kpl] =
          (unsigned char)(((w0 & 15) << 4) | (w1 & 15));
    }
    __syncthreads();
#pragma unroll
    for (int i = 0; i < 4; ++i) {
      const int lin = t + 256 * i;
      const int n16 = lin & 15;
      const int kp4l = (lin >> 4) & 7;
      const int nb16l = lin >> 7;
      const unsigned v = *(const unsigned*)(Sb + (nb16l * 16 + n16) * 36 + kp4l * 4);
      const size_t D = ((size_t)(nt * 8 + nb16l) * 512 + kt * 8 + kp4l) * 16 + n16;
      codes[D] = v;
    }
  } else if (bid < 6528) {
    // conv_a: unit (m16,k32)=1KB; lane l holds A[m16*16+(l&15)][k32*32+(l>>4)*8..+8)
    const int wid = (bid - 5504) * 4 + (t >> 6);
    const int lane = t & 63;
    const int m16 = wid >> 7, k32 = wid & 127;
    const int m = m16 * 16 + (lane & 15);
    const int k = k32 * 32 + (lane >> 4) * 8;
    const float* src = x + (size_t)m * K_DIM + k;
    f32x4 v0 = *(const f32x4*)src;
    f32x4 v1 = *(const f32x4*)(src + 4);
    u32x4 d;
    d[0] = hpack(v0[0], v0[1]);
    d[1] = hpack(v0[2], v0[3]);
    d[2] = hpack(v1[0], v1[1]);
    d[3] = hpack(v1[2], v1[3]);
    *(u32x4*)(wsa + (size_t)wid * 256 + lane * 4) = d;
  } else {
    const int g = (bid - 6528) * 256 + t;
    if (g < SC_ROW * 2048) {
      const int kp = g / SC_ROW;
      const int nb = g - kp * SC_ROW;
      const float s0 = scales[(size_t)(2 * kp) * SC_ROW + nb];
      const float s1 = scales[(size_t)(2 * kp + 1) * SC_ROW + nb];
      scalesp[(size_t)nb * 2048 + kp] = hpack(s0, s1);
    }
  }
}

// ---- main: fused NF4 GEMM, f16 MFMA, IN-BLOCK k-split reduction ----
// R15: the R9 per-wave kernel is unchanged (6 rounds proved its 65us core is
// invariant); the external reduce pass (12us + 180MB partial traffic) is
// deleted. 512t blocks = 2 k-halves x (2m x 2n) waves; kh=1 waves pass acc
// through padded LDS (2 rounds), kh=0 waves add + bias + single final store.
__global__ __launch_bounds__(512) void nf4_gemm_ib(
    const unsigned* __restrict__ codes, const unsigned* __restrict__ scalesp,
    const unsigned* __restrict__ wsa, const float* __restrict__ bias,
    float* __restrict__ out) {
  __shared__ unsigned LutR[256 * 32];              // 32KB replicated LUT
  __shared__ __align__(16) float Red[2][4][64][20];  // 40KB, lane-stride 20 (pad)

  const int bid = blockIdx.x;          // 344 = 8 XCD * 43
  const int x = bid & 7;
  const int q = bid >> 3;              // 0..42
  const int tile = x * 43 + q;         // XCD x owns one m-slice
  const int m_tile = (tile / 86) * 128;
  const int n_tile = (tile % 86) * 128;

  const int t = threadIdx.x;
  {  // replicated LUT: dword idx = byte*32 + copy; lane uses copy=lane&31
    const int c = t & 31;
    const int b0 = t >> 5;             // 0..15
#pragma unroll
    for (int i = 0; i < 16; ++i) {
      const int b = b0 + 16 * i;
      LutR[b * 32 + c] = hpack(NF4[(b >> 4) & 15], NF4[b & 15]);
    }
  }
  __syncthreads();  // LUT visible

  const int lane = t & 63;
  const int wid = t >> 6;              // 0..7
  const int kh = wid >> 2;             // k-half
  const int sub = wid & 3;             // position within k-half
  const int wm2 = sub >> 1;            // wave m-half (64 rows)
  const int wnh = sub & 1;             // wave n-half (64 cols)
  const int l15 = lane & 15;
  const int kslice = lane >> 4;
  const int lb = lane & 31;
  const int m16w = (m_tile >> 4) + wm2 * 4;
  const int nf0 = (n_tile >> 4) + wnh * 4;
  const int nb64 = (n_tile >> 6) + wnh;

  unsigned cb[4];
#pragma unroll
  for (int j = 0; j < 4; ++j) cb[j] = (unsigned)(nf0 + j) * 8192 + lane;
  const unsigned sb = (unsigned)nb64 * 2048 + kslice * 4;
  unsigned ab[4];
#pragma unroll
  for (int fm = 0; fm < 4; ++fm)
    ab[fm] = (unsigned)(m16w + fm) * 32768 + lane * 4;

  f32x4 acc[4][4];
#pragma unroll
  for (int i = 0; i < 4; ++i)
#pragma unroll
    for (int j = 0; j < 4; ++j) acc[i][j] = (f32x4){0.f, 0.f, 0.f, 0.f};

  const int NS = 64;                   // K/2 per k-half, 32 per step
  const int s_base = kh * NS;

  auto LOAD = [&](int sl, unsigned* c, u32x4& sv, u32x4* A) {
    const unsigned s = (unsigned)(s_base + sl);
#pragma unroll
    for (int j = 0; j < 4; ++j) c[j] = codes[cb[j] + 64u * s];
    sv = *(const u32x4*)(scalesp + sb + 16u * s);
#pragma unroll
    for (int fm = 0; fm < 4; ++fm)
      A[fm] = *(const u32x4*)(wsa + ab[fm] + 256u * s);
  };
  auto STEP = [&](const unsigned* c, const u32x4& sv, const u32x4* A) {
    H8 a[4];
#pragma unroll
    for (int fm = 0; fm < 4; ++fm) a[fm].v = A[fm];
#pragma unroll
    for (int j = 0; j < 4; ++j) {
      const unsigned cw = c[j];
      H8 B;
      B.v[0] = h2mul(LutR[((cw & 255u) << 5) | lb], sv[0]);
      B.v[1] = h2mul(LutR[(((cw >> 8) & 255u) << 5) | lb], sv[1]);
      B.v[2] = h2mul(LutR[(((cw >> 16) & 255u) << 5) | lb], sv[2]);
      B.v[3] = h2mul(LutR[((cw >> 24) << 5) | lb], sv[3]);
#pragma unroll
      for (int fm = 0; fm < 4; ++fm)
        acc[fm][j] = __builtin_amdgcn_mfma_f32_16x16x32_f16(a[fm].h, B.h, acc[fm][j], 0, 0, 0);
    }
  };

  unsigned Xc[4], Yc[4];
  u32x4 Xs, Ys;
  u32x4 XA[4], YA[4];
  LOAD(0, Xc, Xs, XA);
#pragma unroll 1
  for (int s = 0; s < NS; s += 2) {
    LOAD(s + 1, Yc, Ys, YA);           // s+1 <= NS-1 always
    STEP(Xc, Xs, XA);
    if (s + 2 < NS) LOAD(s + 2, Xc, Xs, XA);
    STEP(Yc, Ys, YA);
  }

  // ---- in-block reduction + final store (2 rounds of j-pairs) ----
#pragma unroll 1
  for (int jr = 0; jr < 2; ++jr) {
    if (kh == 1) {
#pragma unroll
      for (int jj = 0; jj < 2; ++jj)
#pragma unroll
        for (int fm = 0; fm < 4; ++fm)
          *(f32x4*)&Red[jj][sub][lane][fm * 4] = acc[fm][jr * 2 + jj];
    }
    __syncthreads();
    if (kh == 0) {
#pragma unroll
      for (int jj = 0; jj < 2; ++jj) {
        const int j = jr * 2 + jj;
        const int gc = n_tile + wnh * 64 + j * 16 + l15;
        const float bi = bias[gc];
#pragma unroll
        for (int fm = 0; fm < 4; ++fm) {
          const f32x4 o = acc[fm][j] + *(const f32x4*)&Red[jj][sub][lane][fm * 4];
#pragma unroll
          for (int r = 0; r < 4; ++r) {
            const int gr = m_tile + wm2 * 64 + fm * 16 + kslice * 4 + r;
            out[(size_t)gr * N_DIM + gc] = o[r] + bi;
          }
        }
      }
    }
    __syncthreads();
  }
}

// ---- fallback (round-1 kernel, proven 155us): used only if ws tiny ----
#define FLDS 72
__global__ __launch_bounds__(256) void nf4_gemm_fused(
    const float* __restrict__ x, const int* __restrict__ packed,
    const float* __restrict__ scales, const float* __restrict__ bias,
    float* __restrict__ out) {
  __shared__ unsigned short AldsF[128 * FLDS];
  __shared__ unsigned short BldsF[128 * FLDS];
  __shared__ float2 Lut[256];
  const int t = threadIdx.x;
  const int bid = blockIdx.x;
  const int swz = (bid & 7) * 43 + (bid >> 3);
  const int m_tile = (swz / 86) * 128;
  const int n_tile = (swz % 86) * 128;
  Lut[t] = make_float2(NF4[(t >> 4) & 15], NF4[t & 15]);
  const int lane = t & 63;
  const int wid = t >> 6;
  const int wm = (wid >> 1) * 64;
  const int wn = (wid & 1) * 64;
  const int l15 = lane & 15;
  const int l4 = lane >> 4;
  f32x4 acc[4][4];
#pragma unroll
  for (int i = 0; i < 4; ++i)
#pragma unroll
    for (int j = 0; j < 4; ++j) acc[i][j] = (f32x4){0.f, 0.f, 0.f, 0.f};
  const int mlane = t & 15;
  const int n_sub = mlane * 8;
  const int k_sub = 4 * (((t >> 4) + mlane) & 15);
  const int c4 = t & 15;
  const int r0 = t >> 4;
  for (int k0 = 0; k0 < K_DIM; k0 += 64) {
    __syncthreads();
#pragma unroll
    for (int i = 0; i < 8; ++i) {
      const int row = r0 + 16 * i;
      f32x4 xv = *(const f32x4*)(x + (size_t)(m_tile + row) * K_DIM + k0 + c4 * 4);
      uint2 d;
      d.x = f2bf(xv[0]) | (f2bf(xv[1]) << 16);
      d.y = f2bf(xv[2]) | (f2bf(xv[3]) << 16);
      *(uint2*)(&AldsF[row * FLDS + c4 * 4]) = d;
    }
    {
      const int* pk = packed + (size_t)(k0 + k_sub) * PK_ROW + ((n_tile + n_sub) >> 1);
      i32x4 w[4];
      float s[4];
#pragma unroll
      for (int kk = 0; kk < 4; ++kk) {
        w[kk] = *(const i32x4*)(pk + (size_t)kk * PK_ROW);
        s[kk] = scales[(size_t)(k0 + k_sub + kk) * SC_ROW + ((n_tile + n_sub) >> 6)];
      }
      float v[4][8];
#pragma unroll
      for (int kk = 0; kk < 4; ++kk)
#pragma unroll
        for (int e = 0; e < 4; ++e) {
          const int b = w[kk][e] & 0xFF;
          const float2 p = Lut[b];
          v[kk][2 * e] = p.x * s[kk];
          v[kk][2 * e + 1] = p.y * s[kk];
        }
#pragma unroll
      for (int j = 0; j < 8; ++j) {
        uint2 d;
        d.x = f2bf(v[0][j]) | (f2bf(v[1][j]) << 16);
        d.y = f2bf(v[2][j]) | (f2bf(v[3][j]) << 16);
        *(uint2*)(&BldsF[(n_sub + j) * FLDS + k_sub]) = d;
      }
    }
    __syncthreads();
#pragma unroll
    for (int ks = 0; ks < 2; ++ks) {
      bf16x8 af[4], bfv[4];
#pragma unroll
      for (int fm = 0; fm < 4; ++fm)
        af[fm] = *(const bf16x8*)(&AldsF[(wm + fm * 16 + l15) * FLDS + ks * 32 + l4 * 8]);
#pragma unroll
      for (int fn = 0; fn < 4; ++fn)
        bfv[fn] = *(const bf16x8*)(&BldsF[(wn + fn * 16 + l15) * FLDS + ks * 32 + l4 * 8]);
#pragma unroll
      for (int fm = 0; fm < 4; ++fm)
#pragma unroll
        for (int fn = 0; fn < 4; ++fn)
          acc[fm][fn] = __builtin_amdgcn_mfma_f32_16x16x32_bf16(af[fm], bfv[fn], acc[fm][fn], 0, 0, 0);
    }
  }
#pragma unroll
  for (int fn = 0; fn < 4; ++fn) {
    const float bi = bias[n_tile + wn + fn * 16 + l15];
#pragma unroll
    for (int fm = 0; fm < 4; ++fm)
#pragma unroll
      for (int r = 0; r < 4; ++r) {
        const int gr = m_tile + wm + fm * 16 + l4 * 4 + r;
        out[(size_t)gr * N_DIM + n_tile + wn + fn * 16 + l15] = acc[fm][fn][r] + bi;
      }
  }
}

extern "C" void kernel_launch(void* const* d_in, const int* in_sizes, int n_in,
                              void* d_out, int out_size, void* d_ws, size_t ws_size,
                              hipStream_t stream) {
  const float* x = (const float*)d_in[0];
  const int* packed = (const int*)d_in[1];
  const float* scales = (const float*)d_in[2];
  const float* bias = (const float*)d_in[3];
  float* out = (float*)d_out;

  const size_t A_BYTES = (size_t)M_DIM * K_DIM * 2;            // 4,194,304
  const size_t C_BYTES = (size_t)688 * 512 * 16 * 4;           // 22,544,384
  const size_t S_BYTES = (size_t)SC_ROW * 2048 * 4;            // 1,409,024
  const size_t need = A_BYTES + C_BYTES + S_BYTES;             // 28.1 MB

  if (ws_size >= need) {
    unsigned* wsa = (unsigned*)d_ws;
    unsigned* codes = (unsigned*)((char*)d_ws + A_BYTES);
    unsigned* scalesp = (unsigned*)((char*)d_ws + A_BYTES + C_BYTES);
    prep_all<<<dim3(7904), dim3(256), 0, stream>>>(x, packed, scales, wsa, codes, scalesp);
    nf4_gemm_ib<<<dim3(344), dim3(512), 0, stream>>>(codes, scalesp, wsa, bias, out);
  } else {
    nf4_gemm_fused<<<dim3(344), dim3(256), 0, stream>>>(x, packed, scales, bias, out);
  }
}

// Round 16
// 100.297 us; speedup vs baseline: 1.5030x; 1.2666x over previous
//
#include <hip/hip_runtime.h>
#include <hip/hip_bf16.h>
#include <hip/hip_fp16.h>
#include <stdint.h>

#define K_DIM 4096
#define N_DIM 11008
#define M_DIM 512
#define PK_ROW 5504          // int32 code-words per k-row (one per n-pair)
#define SC_ROW 172           // scale blocks per k-row

typedef __attribute__((ext_vector_type(4))) float f32x4;
typedef __attribute__((ext_vector_type(4))) int i32x4;
typedef __attribute__((ext_vector_type(4))) unsigned int u32x4;
typedef __attribute__((ext_vector_type(8))) _Float16 half8;
typedef __attribute__((ext_vector_type(8))) short bf16x8;

__constant__ float NF4[16] = {
    -1.0f, -0.6961928009986877f, -0.5250730514526367f, -0.39491748809814453f,
    -0.28444138169288635f, -0.18477343022823334f, -0.09105003625154495f, 0.0f,
    0.07958029955625534f, 0.16093020141124725f, 0.24611230194568634f,
    0.33791524171829224f, 0.44070982933044434f, 0.5626170039176941f,
    0.7229568362236023f, 1.0f};

union H8 { u32x4 v; half8 h; };

__device__ __forceinline__ unsigned h2mul(unsigned a, unsigned b) {
  union { __half2 h; unsigned u; } x, y, r;
  x.u = a; y.u = b;
  r.h = x.h * y.h;           // v_pk_mul_f16
  return r.u;
}
__device__ __forceinline__ unsigned hpack(float a, float b) {
  union { __half2 h; unsigned u; } c;
  c.h = __floats2half2_rn(a, b);
  return c.u;
}
__device__ __forceinline__ unsigned f2bf(float v) {  // for fallback kernel
  union { __hip_bfloat16 h; unsigned short u; } cv;
  cv.h = __float2bfloat16(v);
  return (unsigned)cv.u;
}

// ---- merged pre-pass: codes transpose + A conv + scales pack ----
__global__ __launch_bounds__(256) void prep_all(
    const float* __restrict__ x, const int* __restrict__ packed,
    const float* __restrict__ scales, unsigned* __restrict__ wsa,
    unsigned* __restrict__ codes, unsigned* __restrict__ scalesp) {
  const int bid = blockIdx.x;
  const int t = threadIdx.x;
  if (bid < 5504) {
    // codes: out dword D = ((n>>4)*512 + (kp>>2))*16 + (n&15);
    // byte (n,kp) = code(2kp,n)<<4 | code(2kp+1,n)
    const int kt = bid & 63;
    const int nt = bid >> 6;
    __shared__ unsigned char Sb[128 * 36];
    const int npl = t & 63;
    const int kq = t >> 6;
    const int np = nt * 64 + npl;
#pragma unroll
    for (int i = 0; i < 8; ++i) {
      const int kpl = kq + i * 4;
      const int k = kt * 64 + kpl * 2;
      const int w0 = packed[(size_t)k * PK_ROW + np];
      const int w1 = packed[(size_t)(k + 1) * PK_ROW + np];
      Sb[(npl * 2) * 36 + kpl] =
          (unsigned char)((((w0 >> 4) & 15) << 4) | ((w1 >> 4) & 15));
      Sb[(npl * 2 + 1) * 36 + kpl] =
          (unsigned char)(((w0 & 15) << 4) | (w1 & 15));
    }
    __syncthreads();
#pragma unroll
    for (int i = 0; i < 4; ++i) {
      const int lin = t + 256 * i;
      const int n16 = lin & 15;
      const int kp4l = (lin >> 4) & 7;
      const int nb16l = lin >> 7;
      const unsigned v = *(const unsigned*)(Sb + (nb16l * 16 + n16) * 36 + kp4l * 4);
      const size_t D = ((size_t)(nt * 8 + nb16l) * 512 + kt * 8 + kp4l) * 16 + n16;
      codes[D] = v;
    }
  } else if (bid < 6528) {
    // conv_a: unit (m16,k32)=1KB; lane l holds A[m16*16+(l&15)][k32*32+(l>>4)*8..+8)
    const int wid = (bid - 5504) * 4 + (t >> 6);
    const int lane = t & 63;
    const int m16 = wid >> 7, k32 = wid & 127;
    const int m = m16 * 16 + (lane & 15);
    const int k = k32 * 32 + (lane >> 4) * 8;
    const float* src = x + (size_t)m * K_DIM + k;
    f32x4 v0 = *(const f32x4*)src;
    f32x4 v1 = *(const f32x4*)(src + 4);
    u32x4 d;
    d[0] = hpack(v0[0], v0[1]);
    d[1] = hpack(v0[2], v0[3]);
    d[2] = hpack(v1[0], v1[1]);
    d[3] = hpack(v1[2], v1[3]);
    *(u32x4*)(wsa + (size_t)wid * 256 + lane * 4) = d;
  } else {
    const int g = (bid - 6528) * 256 + t;
    if (g < SC_ROW * 2048) {
      const int kp = g / SC_ROW;
      const int nb = g - kp * SC_ROW;
      const float s0 = scales[(size_t)(2 * kp) * SC_ROW + nb];
      const float s1 = scales[(size_t)(2 * kp + 1) * SC_ROW + nb];
      scalesp[(size_t)nb * 2048 + kp] = hpack(s0, s1);
    }
  }
}

// ---- main: fused NF4 GEMM, f16 MFMA, in-block K-reduction @ grid 688 ----
// R16: per-wave stream is EXACTLY R9-KS2 (the measured 65.3us optimum: NS=64,
// nm=nn=4, 2-deep prefetch). Block re-cut: 256t = 2kh x 2nh over a 64m x 128n
// tile so grid stays 688 (R15's regression was grid 344, not the in-block
// idea). kh=1 waves pass acc via padded LDS; kh=0 waves add+bias+final store.
// Deletes the reduce pass (11us) + 90MB partial writes + 112MB reduce traffic.
// XCD x owns m-tile x: A slice 512KB L2-resident.
__global__ __launch_bounds__(256, 3) void nf4_gemm_ib(
    const unsigned* __restrict__ codes, const unsigned* __restrict__ scalesp,
    const unsigned* __restrict__ wsa, const float* __restrict__ bias,
    float* __restrict__ out) {
  __shared__ unsigned LutR[256 * 32];               // 32KB replicated LUT
  __shared__ __align__(16) float Red[2][2][64][20]; // 20KB, stride 20 (pad)

  const int bid = blockIdx.x;          // 688 = 8 XCD * 86
  const int m_tile = (bid & 7) * 64;   // XCD owns one 64-row m-slice
  const int n_tile = (bid >> 3) * 128;

  const int t = threadIdx.x;
  {  // replicated LUT: dword idx = byte*32 + copy; lane uses copy=lane&31
    const int c = t & 31;
    const int b0 = t >> 5;
#pragma unroll
    for (int i = 0; i < 32; ++i) {
      const int b = b0 + 8 * i;
      LutR[b * 32 + c] = hpack(NF4[(b >> 4) & 15], NF4[b & 15]);
    }
  }
  __syncthreads();  // LUT visible

  const int lane = t & 63;
  const int wid = t >> 6;              // 0..3
  const int kh = wid >> 1;             // k-half
  const int nh = wid & 1;              // n-half (64 cols)
  const int l15 = lane & 15;
  const int kslice = lane >> 4;
  const int lb = lane & 31;
  const int m16w = m_tile >> 4;        // wave covers the block's full 64 m
  const int nf0 = (n_tile >> 4) + nh * 4;
  const int nb64 = (n_tile >> 6) + nh;

  unsigned cb[4];
#pragma unroll
  for (int j = 0; j < 4; ++j) cb[j] = (unsigned)(nf0 + j) * 8192 + lane;
  const unsigned sb = (unsigned)nb64 * 2048 + kslice * 4;
  unsigned ab[4];
#pragma unroll
  for (int fm = 0; fm < 4; ++fm)
    ab[fm] = (unsigned)(m16w + fm) * 32768 + lane * 4;

  f32x4 acc[4][4];
#pragma unroll
  for (int i = 0; i < 4; ++i)
#pragma unroll
    for (int j = 0; j < 4; ++j) acc[i][j] = (f32x4){0.f, 0.f, 0.f, 0.f};

  const int NS = 64;                   // K/2 per k-half, 32 k per step
  const int s_base = kh * NS;

  auto LOAD = [&](int sl, unsigned* c, u32x4& sv, u32x4* A) {
    const unsigned s = (unsigned)(s_base + sl);
#pragma unroll
    for (int j = 0; j < 4; ++j) c[j] = codes[cb[j] + 64u * s];
    sv = *(const u32x4*)(scalesp + sb + 16u * s);
#pragma unroll
    for (int fm = 0; fm < 4; ++fm)
      A[fm] = *(const u32x4*)(wsa + ab[fm] + 256u * s);
  };
  auto STEP = [&](const unsigned* c, const u32x4& sv, const u32x4* A) {
    H8 a[4];
#pragma unroll
    for (int fm = 0; fm < 4; ++fm) a[fm].v = A[fm];
#pragma unroll
    for (int j = 0; j < 4; ++j) {
      const unsigned cw = c[j];
      H8 B;
      B.v[0] = h2mul(LutR[((cw & 255u) << 5) | lb], sv[0]);
      B.v[1] = h2mul(LutR[(((cw >> 8) & 255u) << 5) | lb], sv[1]);
      B.v[2] = h2mul(LutR[(((cw >> 16) & 255u) << 5) | lb], sv[2]);
      B.v[3] = h2mul(LutR[((cw >> 24) << 5) | lb], sv[3]);
#pragma unroll
      for (int fm = 0; fm < 4; ++fm)
        acc[fm][j] = __builtin_amdgcn_mfma_f32_16x16x32_f16(a[fm].h, B.h, acc[fm][j], 0, 0, 0);
    }
  };

  unsigned Xc[4], Yc[4];
  u32x4 Xs, Ys;
  u32x4 XA[4], YA[4];
  LOAD(0, Xc, Xs, XA);
#pragma unroll 1
  for (int s = 0; s < NS; s += 2) {
    LOAD(s + 1, Yc, Ys, YA);           // s+1 <= NS-1 always
    STEP(Xc, Xs, XA);
    if (s + 2 < NS) LOAD(s + 2, Xc, Xs, XA);
    STEP(Yc, Ys, YA);
  }

  // ---- in-block k-reduction + final store (2 rounds of j-pairs) ----
  // kh=1 wave (wid 2,3) shares nh and lane with its kh=0 partner (wid 0,1).
#pragma unroll 1
  for (int jr = 0; jr < 2; ++jr) {
    if (kh == 1) {
#pragma unroll
      for (int jj = 0; jj < 2; ++jj)
#pragma unroll
        for (int fm = 0; fm < 4; ++fm)
          *(f32x4*)&Red[jj][nh][lane][fm * 4] = acc[fm][jr * 2 + jj];
    }
    __syncthreads();
    if (kh == 0) {
#pragma unroll
      for (int jj = 0; jj < 2; ++jj) {
        const int j = jr * 2 + jj;
        const int gc = n_tile + nh * 64 + j * 16 + l15;
        const float bi = bias[gc];
#pragma unroll
        for (int fm = 0; fm < 4; ++fm) {
          const f32x4 o = acc[fm][j] + *(const f32x4*)&Red[jj][nh][lane][fm * 4];
#pragma unroll
          for (int r = 0; r < 4; ++r) {
            const int gr = m_tile + fm * 16 + kslice * 4 + r;
            out[(size_t)gr * N_DIM + gc] = o[r] + bi;
          }
        }
      }
    }
    __syncthreads();
  }
}

// ---- fallback (round-1 kernel, proven 155us): used only if ws tiny ----
#define FLDS 72
__global__ __launch_bounds__(256) void nf4_gemm_fused(
    const float* __restrict__ x, const int* __restrict__ packed,
    const float* __restrict__ scales, const float* __restrict__ bias,
    float* __restrict__ out) {
  __shared__ unsigned short AldsF[128 * FLDS];
  __shared__ unsigned short BldsF[128 * FLDS];
  __shared__ float2 Lut[256];
  const int t = threadIdx.x;
  const int bid = blockIdx.x;
  const int swz = (bid & 7) * 43 + (bid >> 3);
  const int m_tile = (swz / 86) * 128;
  const int n_tile = (swz % 86) * 128;
  Lut[t] = make_float2(NF4[(t >> 4) & 15], NF4[t & 15]);
  const int lane = t & 63;
  const int wid = t >> 6;
  const int wm = (wid >> 1) * 64;
  const int wn = (wid & 1) * 64;
  const int l15 = lane & 15;
  const int l4 = lane >> 4;
  f32x4 acc[4][4];
#pragma unroll
  for (int i = 0; i < 4; ++i)
#pragma unroll
    for (int j = 0; j < 4; ++j) acc[i][j] = (f32x4){0.f, 0.f, 0.f, 0.f};
  const int mlane = t & 15;
  const int n_sub = mlane * 8;
  const int k_sub = 4 * (((t >> 4) + mlane) & 15);
  const int c4 = t & 15;
  const int r0 = t >> 4;
  for (int k0 = 0; k0 < K_DIM; k0 += 64) {
    __syncthreads();
#pragma unroll
    for (int i = 0; i < 8; ++i) {
      const int row = r0 + 16 * i;
      f32x4 xv = *(const f32x4*)(x + (size_t)(m_tile + row) * K_DIM + k0 + c4 * 4);
      uint2 d;
      d.x = f2bf(xv[0]) | (f2bf(xv[1]) << 16);
      d.y = f2bf(xv[2]) | (f2bf(xv[3]) << 16);
      *(uint2*)(&AldsF[row * FLDS + c4 * 4]) = d;
    }
    {
      const int* pk = packed + (size_t)(k0 + k_sub) * PK_ROW + ((n_tile + n_sub) >> 1);
      i32x4 w[4];
      float s[4];
#pragma unroll
      for (int kk = 0; kk < 4; ++kk) {
        w[kk] = *(const i32x4*)(pk + (size_t)kk * PK_ROW);
        s[kk] = scales[(size_t)(k0 + k_sub + kk) * SC_ROW + ((n_tile + n_sub) >> 6)];
      }
      float v[4][8];
#pragma unroll
      for (int kk = 0; kk < 4; ++kk)
#pragma unroll
        for (int e = 0; e < 4; ++e) {
          const int b = w[kk][e] & 0xFF;
          const float2 p = Lut[b];
          v[kk][2 * e] = p.x * s[kk];
          v[kk][2 * e + 1] = p.y * s[kk];
        }
#pragma unroll
      for (int j = 0; j < 8; ++j) {
        uint2 d;
        d.x = f2bf(v[0][j]) | (f2bf(v[1][j]) << 16);
        d.y = f2bf(v[2][j]) | (f2bf(v[3][j]) << 16);
        *(uint2*)(&BldsF[(n_sub + j) * FLDS + k_sub]) = d;
      }
    }
    __syncthreads();
#pragma unroll
    for (int ks = 0; ks < 2; ++ks) {
      bf16x8 af[4], bfv[4];
#pragma unroll
      for (int fm = 0; fm < 4; ++fm)
        af[fm] = *(const bf16x8*)(&AldsF[(wm + fm * 16 + l15) * FLDS + ks * 32 + l4 * 8]);
#pragma unroll
      for (int fn = 0; fn < 4; ++fn)
        bfv[fn] = *(const bf16x8*)(&BldsF[(wn + fn * 16 + l15) * FLDS + ks * 32 + l4 * 8]);
#pragma unroll
      for (int fm = 0; fm < 4; ++fm)
#pragma unroll
        for (int fn = 0; fn < 4; ++fn)
          acc[fm][fn] = __builtin_amdgcn_mfma_f32_16x16x32_bf16(af[fm], bfv[fn], acc[fm][fn], 0, 0, 0);
    }
  }
#pragma unroll
  for (int fn = 0; fn < 4; ++fn) {
    const float bi = bias[n_tile + wn + fn * 16 + l15];
#pragma unroll
    for (int fm = 0; fm < 4; ++fm)
#pragma unroll
      for (int r = 0; r < 4; ++r) {
        const int gr = m_tile + wm + fm * 16 + l4 * 4 + r;
        out[(size_t)gr * N_DIM + n_tile + wn + fn * 16 + l15] = acc[fm][fn][r] + bi;
      }
  }
}

extern "C" void kernel_launch(void* const* d_in, const int* in_sizes, int n_in,
                              void* d_out, int out_size, void* d_ws, size_t ws_size,
                              hipStream_t stream) {
  const float* x = (const float*)d_in[0];
  const int* packed = (const int*)d_in[1];
  const float* scales = (const float*)d_in[2];
  const float* bias = (const float*)d_in[3];
  float* out = (float*)d_out;

  const size_t A_BYTES = (size_t)M_DIM * K_DIM * 2;            // 4,194,304
  const size_t C_BYTES = (size_t)688 * 512 * 16 * 4;           // 22,544,384
  const size_t S_BYTES = (size_t)SC_ROW * 2048 * 4;            // 1,409,024
  const size_t need = A_BYTES + C_BYTES + S_BYTES;             // 28.1 MB

  if (ws_size >= need) {
    unsigned* wsa = (unsigned*)d_ws;
    unsigned* codes = (unsigned*)((char*)d_ws + A_BYTES);
    unsigned* scalesp = (unsigned*)((char*)d_ws + A_BYTES + C_BYTES);
    prep_all<<<dim3(7904), dim3(256), 0, stream>>>(x, packed, scales, wsa, codes, scalesp);
    nf4_gemm_ib<<<dim3(688), dim3(256), 0, stream>>>(codes, scalesp, wsa, bias, out);
  } else {
    nf4_gemm_fused<<<dim3(344), dim3(256), 0, stream>>>(x, packed, scales, bias, out);
  }
}

// Round 17
// 97.742 us; speedup vs baseline: 1.5423x; 1.0261x over previous
//
#include <hip/hip_runtime.h>
#include <hip/hip_bf16.h>
#include <hip/hip_fp16.h>
#include <stdint.h>

#define K_DIM 4096
#define N_DIM 11008
#define M_DIM 512
#define PK_ROW 5504          // int32 code-words per k-row (one per n-pair)
#define SC_ROW 172           // scale blocks per k-row

typedef __attribute__((ext_vector_type(4))) float f32x4;
typedef __attribute__((ext_vector_type(4))) int i32x4;
typedef __attribute__((ext_vector_type(4))) unsigned int u32x4;
typedef __attribute__((ext_vector_type(8))) _Float16 half8;
typedef __attribute__((ext_vector_type(8))) short bf16x8;

__constant__ float NF4[16] = {
    -1.0f, -0.6961928009986877f, -0.5250730514526367f, -0.39491748809814453f,
    -0.28444138169288635f, -0.18477343022823334f, -0.09105003625154495f, 0.0f,
    0.07958029955625534f, 0.16093020141124725f, 0.24611230194568634f,
    0.33791524171829224f, 0.44070982933044434f, 0.5626170039176941f,
    0.7229568362236023f, 1.0f};

union H8 { u32x4 v; half8 h; };

__device__ __forceinline__ unsigned h2mul(unsigned a, unsigned b) {
  union { __half2 h; unsigned u; } x, y, r;
  x.u = a; y.u = b;
  r.h = x.h * y.h;           // v_pk_mul_f16
  return r.u;
}
__device__ __forceinline__ unsigned hpack(float a, float b) {
  union { __half2 h; unsigned u; } c;
  c.h = __floats2half2_rn(a, b);
  return c.u;
}
__device__ __forceinline__ unsigned f2bf(float v) {  // for fallback kernel
  union { __hip_bfloat16 h; unsigned short u; } cv;
  cv.h = __float2bfloat16(v);
  return (unsigned)cv.u;
}

// ---- merged pre-pass: codes transpose + A conv + scales pack ----
__global__ __launch_bounds__(256) void prep_all(
    const float* __restrict__ x, const int* __restrict__ packed,
    const float* __restrict__ scales, unsigned* __restrict__ wsa,
    unsigned* __restrict__ codes, unsigned* __restrict__ scalesp) {
  const int bid = blockIdx.x;
  const int t = threadIdx.x;
  if (bid < 5504) {
    // codes: out dword D = ((n>>4)*512 + (kp>>2))*16 + (n&15);
    // byte (n,kp) = code(2kp,n)<<4 | code(2kp+1,n)
    const int kt = bid & 63;
    const int nt = bid >> 6;
    __shared__ unsigned char Sb[128 * 36];
    const int npl = t & 63;
    const int kq = t >> 6;
    const int np = nt * 64 + npl;
#pragma unroll
    for (int i = 0; i < 8; ++i) {
      const int kpl = kq + i * 4;
      const int k = kt * 64 + kpl * 2;
      const int w0 = packed[(size_t)k * PK_ROW + np];
      const int w1 = packed[(size_t)(k + 1) * PK_ROW + np];
      Sb[(npl * 2) * 36 + kpl] =
          (unsigned char)((((w0 >> 4) & 15) << 4) | ((w1 >> 4) & 15));
      Sb[(npl * 2 + 1) * 36 + kpl] =
          (unsigned char)(((w0 & 15) << 4) | (w1 & 15));
    }
    __syncthreads();
#pragma unroll
    for (int i = 0; i < 4; ++i) {
      const int lin = t + 256 * i;
      const int n16 = lin & 15;
      const int kp4l = (lin >> 4) & 7;
      const int nb16l = lin >> 7;
      const unsigned v = *(const unsigned*)(Sb + (nb16l * 16 + n16) * 36 + kp4l * 4);
      const size_t D = ((size_t)(nt * 8 + nb16l) * 512 + kt * 8 + kp4l) * 16 + n16;
      codes[D] = v;
    }
  } else if (bid < 6528) {
    // conv_a: unit (m16,k32)=1KB; lane l holds A[m16*16+(l&15)][k32*32+(l>>4)*8..+8)
    const int wid = (bid - 5504) * 4 + (t >> 6);
    const int lane = t & 63;
    const int m16 = wid >> 7, k32 = wid & 127;
    const int m = m16 * 16 + (lane & 15);
    const int k = k32 * 32 + (lane >> 4) * 8;
    const float* src = x + (size_t)m * K_DIM + k;
    f32x4 v0 = *(const f32x4*)src;
    f32x4 v1 = *(const f32x4*)(src + 4);
    u32x4 d;
    d[0] = hpack(v0[0], v0[1]);
    d[1] = hpack(v0[2], v0[3]);
    d[2] = hpack(v1[0], v1[1]);
    d[3] = hpack(v1[2], v1[3]);
    *(u32x4*)(wsa + (size_t)wid * 256 + lane * 4) = d;
  } else {
    const int g = (bid - 6528) * 256 + t;
    if (g < SC_ROW * 2048) {
      const int kp = g / SC_ROW;
      const int nb = g - kp * SC_ROW;
      const float s0 = scales[(size_t)(2 * kp) * SC_ROW + nb];
      const float s1 = scales[(size_t)(2 * kp + 1) * SC_ROW + nb];
      scalesp[(size_t)nb * 2048 + kp] = hpack(s0, s1);
    }
  }
}

// ---- main: fused NF4 GEMM, f16 MFMA, in-block K-reduction ----
// R17 = R16 with the XCD mapping fixed: R16's `m_tile = bid&7` made every XCD
// stream ALL 22.5MB of codes (FETCH 51->114MB, GEMM 65->80us). Now XCD x owns
// an n-slice (11|10 n-tiles = 2.75MB codes -> L2-RESIDENT, R5-proven split);
// local&7 walks the 8 m-slices reusing those codes from L2; local>>3 walks n
// reusing each 512KB A m-slice. Per-wave stream + in-block reduction are
// byte-identical to R16 (which deleted the reduce pass: WRITE 90->22.5MB).
__global__ __launch_bounds__(256, 3) void nf4_gemm_ib(
    const unsigned* __restrict__ codes, const unsigned* __restrict__ scalesp,
    const unsigned* __restrict__ wsa, const float* __restrict__ bias,
    float* __restrict__ out) {
  __shared__ unsigned LutR[256 * 32];               // 32KB replicated LUT
  __shared__ __align__(16) float Red[2][2][64][20]; // 20KB, stride 20 (pad)

  const int bid = blockIdx.x;          // 704 = 8 XCD * 88 (16 idle)
  const int x = bid & 7;
  const int local = bid >> 3;          // 0..87
  const int S = (x < 6) ? x * 11 : 66 + (x - 6) * 10;  // XCD n-partition
  const int cnt = (x < 6) ? 11 : 10;   // 86 = 6*11 + 2*10
  if (local >= cnt * 8) return;        // block-uniform early exit
  const int n_tile = (S + (local >> 3)) * 128;
  const int m_tile = (local & 7) * 64;

  const int t = threadIdx.x;
  {  // replicated LUT: dword idx = byte*32 + copy; lane uses copy=lane&31
    const int c = t & 31;
    const int b0 = t >> 5;
#pragma unroll
    for (int i = 0; i < 32; ++i) {
      const int b = b0 + 8 * i;
      LutR[b * 32 + c] = hpack(NF4[(b >> 4) & 15], NF4[b & 15]);
    }
  }
  __syncthreads();  // LUT visible

  const int lane = t & 63;
  const int wid = t >> 6;              // 0..3
  const int kh = wid >> 1;             // k-half
  const int nh = wid & 1;              // n-half (64 cols)
  const int l15 = lane & 15;
  const int kslice = lane >> 4;
  const int lb = lane & 31;
  const int m16w = m_tile >> 4;        // wave covers the block's full 64 m
  const int nf0 = (n_tile >> 4) + nh * 4;
  const int nb64 = (n_tile >> 6) + nh;

  unsigned cb[4];
#pragma unroll
  for (int j = 0; j < 4; ++j) cb[j] = (unsigned)(nf0 + j) * 8192 + lane;
  const unsigned sb = (unsigned)nb64 * 2048 + kslice * 4;
  unsigned ab[4];
#pragma unroll
  for (int fm = 0; fm < 4; ++fm)
    ab[fm] = (unsigned)(m16w + fm) * 32768 + lane * 4;

  f32x4 acc[4][4];
#pragma unroll
  for (int i = 0; i < 4; ++i)
#pragma unroll
    for (int j = 0; j < 4; ++j) acc[i][j] = (f32x4){0.f, 0.f, 0.f, 0.f};

  const int NS = 64;                   // K/2 per k-half, 32 k per step
  const int s_base = kh * NS;

  auto LOAD = [&](int sl, unsigned* c, u32x4& sv, u32x4* A) {
    const unsigned s = (unsigned)(s_base + sl);
#pragma unroll
    for (int j = 0; j < 4; ++j) c[j] = codes[cb[j] + 64u * s];
    sv = *(const u32x4*)(scalesp + sb + 16u * s);
#pragma unroll
    for (int fm = 0; fm < 4; ++fm)
      A[fm] = *(const u32x4*)(wsa + ab[fm] + 256u * s);
  };
  auto STEP = [&](const unsigned* c, const u32x4& sv, const u32x4* A) {
    H8 a[4];
#pragma unroll
    for (int fm = 0; fm < 4; ++fm) a[fm].v = A[fm];
#pragma unroll
    for (int j = 0; j < 4; ++j) {
      const unsigned cw = c[j];
      H8 B;
      B.v[0] = h2mul(LutR[((cw & 255u) << 5) | lb], sv[0]);
      B.v[1] = h2mul(LutR[(((cw >> 8) & 255u) << 5) | lb], sv[1]);
      B.v[2] = h2mul(LutR[(((cw >> 16) & 255u) << 5) | lb], sv[2]);
      B.v[3] = h2mul(LutR[((cw >> 24) << 5) | lb], sv[3]);
#pragma unroll
      for (int fm = 0; fm < 4; ++fm)
        acc[fm][j] = __builtin_amdgcn_mfma_f32_16x16x32_f16(a[fm].h, B.h, acc[fm][j], 0, 0, 0);
    }
  };

  unsigned Xc[4], Yc[4];
  u32x4 Xs, Ys;
  u32x4 XA[4], YA[4];
  LOAD(0, Xc, Xs, XA);
#pragma unroll 1
  for (int s = 0; s < NS; s += 2) {
    LOAD(s + 1, Yc, Ys, YA);           // s+1 <= NS-1 always
    STEP(Xc, Xs, XA);
    if (s + 2 < NS) LOAD(s + 2, Xc, Xs, XA);
    STEP(Yc, Ys, YA);
  }

  // ---- in-block k-reduction + final store (2 rounds of j-pairs) ----
  // kh=1 wave (wid 2,3) shares nh and lane with its kh=0 partner (wid 0,1).
#pragma unroll 1
  for (int jr = 0; jr < 2; ++jr) {
    if (kh == 1) {
#pragma unroll
      for (int jj = 0; jj < 2; ++jj)
#pragma unroll
        for (int fm = 0; fm < 4; ++fm)
          *(f32x4*)&Red[jj][nh][lane][fm * 4] = acc[fm][jr * 2 + jj];
    }
    __syncthreads();
    if (kh == 0) {
#pragma unroll
      for (int jj = 0; jj < 2; ++jj) {
        const int j = jr * 2 + jj;
        const int gc = n_tile + nh * 64 + j * 16 + l15;
        const float bi = bias[gc];
#pragma unroll
        for (int fm = 0; fm < 4; ++fm) {
          const f32x4 o = acc[fm][j] + *(const f32x4*)&Red[jj][nh][lane][fm * 4];
#pragma unroll
          for (int r = 0; r < 4; ++r) {
            const int gr = m_tile + fm * 16 + kslice * 4 + r;
            out[(size_t)gr * N_DIM + gc] = o[r] + bi;
          }
        }
      }
    }
    __syncthreads();
  }
}

// ---- fallback (round-1 kernel, proven 155us): used only if ws tiny ----
#define FLDS 72
__global__ __launch_bounds__(256) void nf4_gemm_fused(
    const float* __restrict__ x, const int* __restrict__ packed,
    const float* __restrict__ scales, const float* __restrict__ bias,
    float* __restrict__ out) {
  __shared__ unsigned short AldsF[128 * FLDS];
  __shared__ unsigned short BldsF[128 * FLDS];
  __shared__ float2 Lut[256];
  const int t = threadIdx.x;
  const int bid = blockIdx.x;
  const int swz = (bid & 7) * 43 + (bid >> 3);
  const int m_tile = (swz / 86) * 128;
  const int n_tile = (swz % 86) * 128;
  Lut[t] = make_float2(NF4[(t >> 4) & 15], NF4[t & 15]);
  const int lane = t & 63;
  const int wid = t >> 6;
  const int wm = (wid >> 1) * 64;
  const int wn = (wid & 1) * 64;
  const int l15 = lane & 15;
  const int l4 = lane >> 4;
  f32x4 acc[4][4];
#pragma unroll
  for (int i = 0; i < 4; ++i)
#pragma unroll
    for (int j = 0; j < 4; ++j) acc[i][j] = (f32x4){0.f, 0.f, 0.f, 0.f};
  const int mlane = t & 15;
  const int n_sub = mlane * 8;
  const int k_sub = 4 * (((t >> 4) + mlane) & 15);
  const int c4 = t & 15;
  const int r0 = t >> 4;
  for (int k0 = 0; k0 < K_DIM; k0 += 64) {
    __syncthreads();
#pragma unroll
    for (int i = 0; i < 8; ++i) {
      const int row = r0 + 16 * i;
      f32x4 xv = *(const f32x4*)(x + (size_t)(m_tile + row) * K_DIM + k0 + c4 * 4);
      uint2 d;
      d.x = f2bf(xv[0]) | (f2bf(xv[1]) << 16);
      d.y = f2bf(xv[2]) | (f2bf(xv[3]) << 16);
      *(uint2*)(&AldsF[row * FLDS + c4 * 4]) = d;
    }
    {
      const int* pk = packed + (size_t)(k0 + k_sub) * PK_ROW + ((n_tile + n_sub) >> 1);
      i32x4 w[4];
      float s[4];
#pragma unroll
      for (int kk = 0; kk < 4; ++kk) {
        w[kk] = *(const i32x4*)(pk + (size_t)kk * PK_ROW);
        s[kk] = scales[(size_t)(k0 + k_sub + kk) * SC_ROW + ((n_tile + n_sub) >> 6)];
      }
      float v[4][8];
#pragma unroll
      for (int kk = 0; kk < 4; ++kk)
#pragma unroll
        for (int e = 0; e < 4; ++e) {
          const int b = w[kk][e] & 0xFF;
          const float2 p = Lut[b];
          v[kk][2 * e] = p.x * s[kk];
          v[kk][2 * e + 1] = p.y * s[kk];
        }
#pragma unroll
      for (int j = 0; j < 8; ++j) {
        uint2 d;
        d.x = f2bf(v[0][j]) | (f2bf(v[1][j]) << 16);
        d.y = f2bf(v[2][j]) | (f2bf(v[3][j]) << 16);
        *(uint2*)(&BldsF[(n_sub + j) * FLDS + k_sub]) = d;
      }
    }
    __syncthreads();
#pragma unroll
    for (int ks = 0; ks < 2; ++ks) {
      bf16x8 af[4], bfv[4];
#pragma unroll
      for (int fm = 0; fm < 4; ++fm)
        af[fm] = *(const bf16x8*)(&AldsF[(wm + fm * 16 + l15) * FLDS + ks * 32 + l4 * 8]);
#pragma unroll
      for (int fn = 0; fn < 4; ++fn)
        bfv[fn] = *(const bf16x8*)(&BldsF[(wn + fn * 16 + l15) * FLDS + ks * 32 + l4 * 8]);
#pragma unroll
      for (int fm = 0; fm < 4; ++fm)
#pragma unroll
        for (int fn = 0; fn < 4; ++fn)
          acc[fm][fn] = __builtin_amdgcn_mfma_f32_16x16x32_bf16(af[fm], bfv[fn], acc[fm][fn], 0, 0, 0);
    }
  }
#pragma unroll
  for (int fn = 0; fn < 4; ++fn) {
    const float bi = bias[n_tile + wn + fn * 16 + l15];
#pragma unroll
    for (int fm = 0; fm < 4; ++fm)
#pragma unroll
      for (int r = 0; r < 4; ++r) {
        const int gr = m_tile + wm + fm * 16 + l4 * 4 + r;
        out[(size_t)gr * N_DIM + n_tile + wn + fn * 16 + l15] = acc[fm][fn][r] + bi;
      }
  }
}

extern "C" void kernel_launch(void* const* d_in, const int* in_sizes, int n_in,
                              void* d_out, int out_size, void* d_ws, size_t ws_size,
                              hipStream_t stream) {
  const float* x = (const float*)d_in[0];
  const int* packed = (const int*)d_in[1];
  const float* scales = (const float*)d_in[2];
  const float* bias = (const float*)d_in[3];
  float* out = (float*)d_out;

  const size_t A_BYTES = (size_t)M_DIM * K_DIM * 2;            // 4,194,304
  const size_t C_BYTES = (size_t)688 * 512 * 16 * 4;           // 22,544,384
  const size_t S_BYTES = (size_t)SC_ROW * 2048 * 4;            // 1,409,024
  const size_t need = A_BYTES + C_BYTES + S_BYTES;             // 28.1 MB

  if (ws_size >= need) {
    unsigned* wsa = (unsigned*)d_ws;
    unsigned* codes = (unsigned*)((char*)d_ws + A_BYTES);
    unsigned* scalesp = (unsigned*)((char*)d_ws + A_BYTES + C_BYTES);
    prep_all<<<dim3(7904), dim3(256), 0, stream>>>(x, packed, scales, wsa, codes, scalesp);
    nf4_gemm_ib<<<dim3(704), dim3(256), 0, stream>>>(codes, scalesp, wsa, bias, out);
  } else {
    nf4_gemm_fused<<<dim3(344), dim3(256), 0, stream>>>(x, packed, scales, bias, out);
  }
}

// Round 18
// 83.230 us; speedup vs baseline: 1.8113x; 1.1744x over previous
//
#include <hip/hip_runtime.h>
#include <hip/hip_bf16.h>
#include <hip/hip_fp16.h>
#include <stdint.h>

#define K_DIM 4096
#define N_DIM 11008
#define M_DIM 512
#define PK_ROW 5504          // int32 code-words per k-row (one per n-pair)
#define SC_ROW 172           // scale blocks per k-row

typedef __attribute__((ext_vector_type(4))) float f32x4;
typedef __attribute__((ext_vector_type(4))) int i32x4;
typedef __attribute__((ext_vector_type(4))) unsigned int u32x4;
typedef __attribute__((ext_vector_type(8))) _Float16 half8;
typedef __attribute__((ext_vector_type(8))) short bf16x8;

__constant__ float NF4[16] = {
    -1.0f, -0.6961928009986877f, -0.5250730514526367f, -0.39491748809814453f,
    -0.28444138169288635f, -0.18477343022823334f, -0.09105003625154495f, 0.0f,
    0.07958029955625534f, 0.16093020141124725f, 0.24611230194568634f,
    0.33791524171829224f, 0.44070982933044434f, 0.5626170039176941f,
    0.7229568362236023f, 1.0f};

union H8 { u32x4 v; half8 h; };

__device__ __forceinline__ unsigned h2mul(unsigned a, unsigned b) {
  union { __half2 h; unsigned u; } x, y, r;
  x.u = a; y.u = b;
  r.h = x.h * y.h;           // v_pk_mul_f16
  return r.u;
}
__device__ __forceinline__ unsigned hpack(float a, float b) {
  union { __half2 h; unsigned u; } c;
  c.h = __floats2half2_rn(a, b);
  return c.u;
}
__device__ __forceinline__ unsigned f2bf(float v) {  // for fallback kernel
  union { __hip_bfloat16 h; unsigned short u; } cv;
  cv.h = __float2bfloat16(v);
  return (unsigned)cv.u;
}

// ---- merged pre-pass: codes transpose + A conv + scales pack ----
__global__ __launch_bounds__(256) void prep_all(
    const float* __restrict__ x, const int* __restrict__ packed,
    const float* __restrict__ scales, unsigned* __restrict__ wsa,
    unsigned* __restrict__ codes, unsigned* __restrict__ scalesp) {
  const int bid = blockIdx.x;
  const int t = threadIdx.x;
  if (bid < 5504) {
    // codes: out dword D = ((n>>4)*512 + (kp>>2))*16 + (n&15);
    // byte (n,kp) = code(2kp,n)<<4 | code(2kp+1,n)
    const int kt = bid & 63;
    const int nt = bid >> 6;
    __shared__ unsigned char Sb[128 * 36];
    const int npl = t & 63;
    const int kq = t >> 6;
    const int np = nt * 64 + npl;
#pragma unroll
    for (int i = 0; i < 8; ++i) {
      const int kpl = kq + i * 4;
      const int k = kt * 64 + kpl * 2;
      const int w0 = packed[(size_t)k * PK_ROW + np];
      const int w1 = packed[(size_t)(k + 1) * PK_ROW + np];
      Sb[(npl * 2) * 36 + kpl] =
          (unsigned char)((((w0 >> 4) & 15) << 4) | ((w1 >> 4) & 15));
      Sb[(npl * 2 + 1) * 36 + kpl] =
          (unsigned char)(((w0 & 15) << 4) | (w1 & 15));
    }
    __syncthreads();
#pragma unroll
    for (int i = 0; i < 4; ++i) {
      const int lin = t + 256 * i;
      const int n16 = lin & 15;
      const int kp4l = (lin >> 4) & 7;
      const int nb16l = lin >> 7;
      const unsigned v = *(const unsigned*)(Sb + (nb16l * 16 + n16) * 36 + kp4l * 4);
      const size_t D = ((size_t)(nt * 8 + nb16l) * 512 + kt * 8 + kp4l) * 16 + n16;
      codes[D] = v;
    }
  } else if (bid < 6528) {
    // conv_a: unit (m16,k32)=1KB; lane l holds A[m16*16+(l&15)][k32*32+(l>>4)*8..+8)
    const int wid = (bid - 5504) * 4 + (t >> 6);
    const int lane = t & 63;
    const int m16 = wid >> 7, k32 = wid & 127;
    const int m = m16 * 16 + (lane & 15);
    const int k = k32 * 32 + (lane >> 4) * 8;
    const float* src = x + (size_t)m * K_DIM + k;
    f32x4 v0 = *(const f32x4*)src;
    f32x4 v1 = *(const f32x4*)(src + 4);
    u32x4 d;
    d[0] = hpack(v0[0], v0[1]);
    d[1] = hpack(v0[2], v0[3]);
    d[2] = hpack(v1[0], v1[1]);
    d[3] = hpack(v1[2], v1[3]);
    *(u32x4*)(wsa + (size_t)wid * 256 + lane * 4) = d;
  } else {
    const int g = (bid - 6528) * 256 + t;
    if (g < SC_ROW * 2048) {
      const int kp = g / SC_ROW;
      const int nb = g - kp * SC_ROW;
      const float s0 = scales[(size_t)(2 * kp) * SC_ROW + nb];
      const float s1 = scales[(size_t)(2 * kp + 1) * SC_ROW + nb];
      scalesp[(size_t)nb * 2048 + kp] = hpack(s0, s1);
    }
  }
}

// ---- main: fused NF4 GEMM, f16 MFMA, in-block K-reduction ----
// R18 = R17 with the epilogue store path densified. R17 diagnosis: scalar
// dword stores deliver 64B/row/instr -> partial-line flush inflated WRITE to
// 110MB for a 22.5MB output (= the 65->80us regression vs R9; partial-store
// kernels measured ~1x). Fix: reduce + accumulate into a 64x132 LDS out-tile,
// then ALL waves stream it with f32x4 stores (2 rows x 512B contiguous per
// instr = full 128B lines). LUT 32->16 copies (lane&15; 2-way = free) keeps
// LDS at ~49KB -> 3 blocks/CU.
__global__ __launch_bounds__(256, 3) void nf4_gemm_ib(
    const unsigned* __restrict__ codes, const unsigned* __restrict__ scalesp,
    const unsigned* __restrict__ wsa, const float* __restrict__ bias,
    float* __restrict__ out) {
  __shared__ unsigned LutR[256 * 16];       // 16-copy replicated LUT (16KB)
  __shared__ __align__(16) float Otile[64][132];  // 33.8KB, pad 132

  const int bid = blockIdx.x;          // 704 = 8 XCD * 88 (16 idle)
  const int x = bid & 7;
  const int local = bid >> 3;          // 0..87
  const int S = (x < 6) ? x * 11 : 66 + (x - 6) * 10;  // XCD n-partition
  const int cnt = (x < 6) ? 11 : 10;   // 86 = 6*11 + 2*10
  if (local >= cnt * 8) return;        // block-uniform early exit
  const int n_tile = (S + (local >> 3)) * 128;
  const int m_tile = (local & 7) * 64;

  const int t = threadIdx.x;
  {  // replicated LUT: dword idx = byte*16 + copy; lane uses copy=lane&15
    const int c = t & 15;
    const int b0 = t >> 4;             // 0..15
#pragma unroll
    for (int i = 0; i < 16; ++i) {
      const int b = b0 + 16 * i;
      LutR[b * 16 + c] = hpack(NF4[(b >> 4) & 15], NF4[b & 15]);
    }
  }
  __syncthreads();  // LUT visible

  const int lane = t & 63;
  const int wid = t >> 6;              // 0..3
  const int kh = wid >> 1;             // k-half
  const int nh = wid & 1;              // n-half (64 cols)
  const int l15 = lane & 15;
  const int kslice = lane >> 4;
  const int lb = lane & 15;            // LUT copy index
  const int m16w = m_tile >> 4;        // wave covers the block's full 64 m
  const int nf0 = (n_tile >> 4) + nh * 4;
  const int nb64 = (n_tile >> 6) + nh;

  unsigned cb[4];
#pragma unroll
  for (int j = 0; j < 4; ++j) cb[j] = (unsigned)(nf0 + j) * 8192 + lane;
  const unsigned sb = (unsigned)nb64 * 2048 + kslice * 4;
  unsigned ab[4];
#pragma unroll
  for (int fm = 0; fm < 4; ++fm)
    ab[fm] = (unsigned)(m16w + fm) * 32768 + lane * 4;

  f32x4 acc[4][4];
#pragma unroll
  for (int i = 0; i < 4; ++i)
#pragma unroll
    for (int j = 0; j < 4; ++j) acc[i][j] = (f32x4){0.f, 0.f, 0.f, 0.f};

  const int NS = 64;                   // K/2 per k-half, 32 k per step
  const int s_base = kh * NS;

  auto LOAD = [&](int sl, unsigned* c, u32x4& sv, u32x4* A) {
    const unsigned s = (unsigned)(s_base + sl);
#pragma unroll
    for (int j = 0; j < 4; ++j) c[j] = codes[cb[j] + 64u * s];
    sv = *(const u32x4*)(scalesp + sb + 16u * s);
#pragma unroll
    for (int fm = 0; fm < 4; ++fm)
      A[fm] = *(const u32x4*)(wsa + ab[fm] + 256u * s);
  };
  auto STEP = [&](const unsigned* c, const u32x4& sv, const u32x4* A) {
    H8 a[4];
#pragma unroll
    for (int fm = 0; fm < 4; ++fm) a[fm].v = A[fm];
#pragma unroll
    for (int j = 0; j < 4; ++j) {
      const unsigned cw = c[j];
      H8 B;
      B.v[0] = h2mul(LutR[((cw & 255u) << 4) | lb], sv[0]);
      B.v[1] = h2mul(LutR[(((cw >> 8) & 255u) << 4) | lb], sv[1]);
      B.v[2] = h2mul(LutR[(((cw >> 16) & 255u) << 4) | lb], sv[2]);
      B.v[3] = h2mul(LutR[((cw >> 24) << 4) | lb], sv[3]);
#pragma unroll
      for (int fm = 0; fm < 4; ++fm)
        acc[fm][j] = __builtin_amdgcn_mfma_f32_16x16x32_f16(a[fm].h, B.h, acc[fm][j], 0, 0, 0);
    }
  };

  unsigned Xc[4], Yc[4];
  u32x4 Xs, Ys;
  u32x4 XA[4], YA[4];
  LOAD(0, Xc, Xs, XA);
#pragma unroll 1
  for (int s = 0; s < NS; s += 2) {
    LOAD(s + 1, Yc, Ys, YA);           // s+1 <= NS-1 always
    STEP(Xc, Xs, XA);
    if (s + 2 < NS) LOAD(s + 2, Xc, Xs, XA);
    STEP(Yc, Ys, YA);
  }

  // ---- epilogue: reduce into LDS out-tile, then dense f32x4 streaming ----
  // deposit (kh=1): scalar LDS writes; banks: (row*132 + col) with kslice-row
  // stride -> 2-way max = free.
  if (kh == 1) {
#pragma unroll
    for (int j = 0; j < 4; ++j)
#pragma unroll
      for (int fm = 0; fm < 4; ++fm)
#pragma unroll
        for (int r = 0; r < 4; ++r)
          Otile[fm * 16 + kslice * 4 + r][nh * 64 + j * 16 + l15] = acc[fm][j][r];
  }
  __syncthreads();
  if (kh == 0) {
#pragma unroll
    for (int j = 0; j < 4; ++j) {
      const float bi = bias[n_tile + nh * 64 + j * 16 + l15];
#pragma unroll
      for (int fm = 0; fm < 4; ++fm)
#pragma unroll
        for (int r = 0; r < 4; ++r) {
          const int row = fm * 16 + kslice * 4 + r;
          const int col = nh * 64 + j * 16 + l15;
          Otile[row][col] += acc[fm][j][r] + bi;
        }
    }
  }
  __syncthreads();
  // stream: all 4 waves; per instr 64 lanes = 2 rows x 32 lanes x 16B
  // (512B contiguous per row = 4 full 128B lines).
  {
    const int c8 = lane & 31;          // 32 cols of f32x4
    const int r2 = lane >> 5;          // row within pair
#pragma unroll
    for (int it = 0; it < 8; ++it) {
      const int row = it * 8 + wid * 2 + r2;
      const f32x4 v = *(const f32x4*)&Otile[row][c8 * 4];
      *(f32x4*)&out[(size_t)(m_tile + row) * N_DIM + n_tile + c8 * 4] = v;
    }
  }
}

// ---- fallback (round-1 kernel, proven 155us): used only if ws tiny ----
#define FLDS 72
__global__ __launch_bounds__(256) void nf4_gemm_fused(
    const float* __restrict__ x, const int* __restrict__ packed,
    const float* __restrict__ scales, const float* __restrict__ bias,
    float* __restrict__ out) {
  __shared__ unsigned short AldsF[128 * FLDS];
  __shared__ unsigned short BldsF[128 * FLDS];
  __shared__ float2 Lut[256];
  const int t = threadIdx.x;
  const int bid = blockIdx.x;
  const int swz = (bid & 7) * 43 + (bid >> 3);
  const int m_tile = (swz / 86) * 128;
  const int n_tile = (swz % 86) * 128;
  Lut[t] = make_float2(NF4[(t >> 4) & 15], NF4[t & 15]);
  const int lane = t & 63;
  const int wid = t >> 6;
  const int wm = (wid >> 1) * 64;
  const int wn = (wid & 1) * 64;
  const int l15 = lane & 15;
  const int l4 = lane >> 4;
  f32x4 acc[4][4];
#pragma unroll
  for (int i = 0; i < 4; ++i)
#pragma unroll
    for (int j = 0; j < 4; ++j) acc[i][j] = (f32x4){0.f, 0.f, 0.f, 0.f};
  const int mlane = t & 15;
  const int n_sub = mlane * 8;
  const int k_sub = 4 * (((t >> 4) + mlane) & 15);
  const int c4 = t & 15;
  const int r0 = t >> 4;
  for (int k0 = 0; k0 < K_DIM; k0 += 64) {
    __syncthreads();
#pragma unroll
    for (int i = 0; i < 8; ++i) {
      const int row = r0 + 16 * i;
      f32x4 xv = *(const f32x4*)(x + (size_t)(m_tile + row) * K_DIM + k0 + c4 * 4);
      uint2 d;
      d.x = f2bf(xv[0]) | (f2bf(xv[1]) << 16);
      d.y = f2bf(xv[2]) | (f2bf(xv[3]) << 16);
      *(uint2*)(&AldsF[row * FLDS + c4 * 4]) = d;
    }
    {
      const int* pk = packed + (size_t)(k0 + k_sub) * PK_ROW + ((n_tile + n_sub) >> 1);
      i32x4 w[4];
      float s[4];
#pragma unroll
      for (int kk = 0; kk < 4; ++kk) {
        w[kk] = *(const i32x4*)(pk + (size_t)kk * PK_ROW);
        s[kk] = scales[(size_t)(k0 + k_sub + kk) * SC_ROW + ((n_tile + n_sub) >> 6)];
      }
      float v[4][8];
#pragma unroll
      for (int kk = 0; kk < 4; ++kk)
#pragma unroll
        for (int e = 0; e < 4; ++e) {
          const int b = w[kk][e] & 0xFF;
          const float2 p = Lut[b];
          v[kk][2 * e] = p.x * s[kk];
          v[kk][2 * e + 1] = p.y * s[kk];
        }
#pragma unroll
      for (int j = 0; j < 8; ++j) {
        uint2 d;
        d.x = f2bf(v[0][j]) | (f2bf(v[1][j]) << 16);
        d.y = f2bf(v[2][j]) | (f2bf(v[3][j]) << 16);
        *(uint2*)(&BldsF[(n_sub + j) * FLDS + k_sub]) = d;
      }
    }
    __syncthreads();
#pragma unroll
    for (int ks = 0; ks < 2; ++ks) {
      bf16x8 af[4], bfv[4];
#pragma unroll
      for (int fm = 0; fm < 4; ++fm)
        af[fm] = *(const bf16x8*)(&AldsF[(wm + fm * 16 + l15) * FLDS + ks * 32 + l4 * 8]);
#pragma unroll
      for (int fn = 0; fn < 4; ++fn)
        bfv[fn] = *(const bf16x8*)(&BldsF[(wn + fn * 16 + l15) * FLDS + ks * 32 + l4 * 8]);
#pragma unroll
      for (int fm = 0; fm < 4; ++fm)
#pragma unroll
        for (int fn = 0; fn < 4; ++fn)
          acc[fm][fn] = __builtin_amdgcn_mfma_f32_16x16x32_bf16(af[fm], bfv[fn], acc[fm][fn], 0, 0, 0);
    }
  }
#pragma unroll
  for (int fn = 0; fn < 4; ++fn) {
    const float bi = bias[n_tile + wn + fn * 16 + l15];
#pragma unroll
    for (int fm = 0; fm < 4; ++fm)
#pragma unroll
      for (int r = 0; r < 4; ++r) {
        const int gr = m_tile + wm + fm * 16 + l4 * 4 + r;
        out[(size_t)gr * N_DIM + n_tile + wn + fn * 16 + l15] = acc[fm][fn][r] + bi;
      }
  }
}

extern "C" void kernel_launch(void* const* d_in, const int* in_sizes, int n_in,
                              void* d_out, int out_size, void* d_ws, size_t ws_size,
                              hipStream_t stream) {
  const float* x = (const float*)d_in[0];
  const int* packed = (const int*)d_in[1];
  const float* scales = (const float*)d_in[2];
  const float* bias = (const float*)d_in[3];
  float* out = (float*)d_out;

  const size_t A_BYTES = (size_t)M_DIM * K_DIM * 2;            // 4,194,304
  const size_t C_BYTES = (size_t)688 * 512 * 16 * 4;           // 22,544,384
  const size_t S_BYTES = (size_t)SC_ROW * 2048 * 4;            // 1,409,024
  const size_t need = A_BYTES + C_BYTES + S_BYTES;             // 28.1 MB

  if (ws_size >= need) {
    unsigned* wsa = (unsigned*)d_ws;
    unsigned* codes = (unsigned*)((char*)d_ws + A_BYTES);
    unsigned* scalesp = (unsigned*)((char*)d_ws + A_BYTES + C_BYTES);
    prep_all<<<dim3(7904), dim3(256), 0, stream>>>(x, packed, scales, wsa, codes, scalesp);
    nf4_gemm_ib<<<dim3(704), dim3(256), 0, stream>>>(codes, scalesp, wsa, bias, out);
  } else {
    nf4_gemm_fused<<<dim3(344), dim3(256), 0, stream>>>(x, packed, scales, bias, out);
  }
}